// Round 1
// baseline (523.420 us; speedup 1.0000x reference)
//
#include <hip/hip_runtime.h>

// EMA y_t = w*x_t + (1-w)*y_{t-1}, a = 1-w per-channel constant.
// SINGLE fused kernel, chunk length L=64, P = T/L = 128 chunks per batch row.
//
// Per (b,p) block (64 threads = 1 wave, 4 channels/lane):
//   phase A: local scan with zero seed -> chunk_last[b,p,:], publish flag
//            (release, agent scope: visible across XCDs)
//   carry:   spin (acquire) on predecessor flags, redundant prefix scan of
//            chunk_last[b,0..p-1,:] (L2/L3-resident, no serial chain)
//   phase B: re-stream the chunk (x L2/L3-warm from phase A), write out.
//
// vs the 2-kernel version: no grid-wide barrier between phases (early blocks
// write output while late blocks still scan -> HBM read/write overlap), one
// launch, no inter-kernel gap. All 2048 one-wave blocks are co-resident
// (8 blocks/CU), so predecessor spins cannot deadlock.

#define CHUNK_L 64

__device__ __forceinline__ float clip01(float v) {
    return fminf(fmaxf(v, 0.0f), 1.0f);
}

__global__ __launch_bounds__(64) void ema_fused(
    const float* __restrict__ x, const float* __restrict__ smooth,
    const float* __restrict__ init, float* __restrict__ out,
    float* __restrict__ chunk_last, unsigned int* __restrict__ flags,
    int T, int C, int P) {
    const int blk = blockIdx.x;          // b*P + p
    const int b = blk / P;
    const int p = blk - b * P;
    const int c = threadIdx.x << 2;

    float4 w4 = *(const float4*)(smooth + c);
    w4.x = clip01(w4.x); w4.y = clip01(w4.y); w4.z = clip01(w4.z); w4.w = clip01(w4.w);
    const float ax = 1.0f - w4.x, ay = 1.0f - w4.y, az = 1.0f - w4.z, aw = 1.0f - w4.w;

    const int sF4 = C >> 2;
    const size_t base = ((size_t)b * T + (size_t)p * CHUNK_L) * C;
    const float4* xp = (const float4*)(x + base) + threadIdx.x;

    // ---- phase A: zero-seeded local scan -> chunk aggregate ----
    float y0 = 0.0f, y1 = 0.0f, y2 = 0.0f, y3 = 0.0f;
    for (int i0 = 0; i0 < CHUNK_L; i0 += 8) {
        float4 xv[8];
#pragma unroll
        for (int j = 0; j < 8; ++j) xv[j] = xp[(size_t)(i0 + j) * sF4];
#pragma unroll
        for (int j = 0; j < 8; ++j) {
            y0 = fmaf(ax, y0, w4.x * xv[j].x);
            y1 = fmaf(ay, y1, w4.y * xv[j].y);
            y2 = fmaf(az, y2, w4.z * xv[j].z);
            y3 = fmaf(aw, y3, w4.w * xv[j].w);
        }
    }
    {
        float4 r; r.x = y0; r.y = y1; r.z = y2; r.w = y3;
        *(float4*)(chunk_last + (size_t)blk * C + c) = r;
    }
    // Publish: release-store at agent scope orders the wave's chunk_last
    // stores (s_waitcnt vmcnt(0) + L2 writeback) before the flag becomes
    // visible on other XCDs.
    if (threadIdx.x == 0) {
        __hip_atomic_store(flags + blk, 1u, __ATOMIC_RELEASE, __HIP_MEMORY_SCOPE_AGENT);
    }

    // aL = a^CHUNK_L by repeated squaring (6 squarings for L=64)
    float aLx = ax, aLy = ay, aLz = az, aLw = aw;
    for (int e = CHUNK_L; e > 1; e >>= 1) { aLx *= aLx; aLy *= aLy; aLz *= aLz; aLw *= aLw; }

    // ---- carry-in: redundant prefix scan of predecessors' aggregates ----
    float4 s = *(const float4*)(init + (size_t)b * C + c);
    const float* cl = chunk_last + (size_t)b * P * C + c;
    const unsigned int* fl = flags + (size_t)b * P;
    int q = 0;
    for (; q + 8 <= p; q += 8) {
        // lanes 0..7 spin on flags[q..q+7]; acquire invalidates stale cache
        // lines so the whole wave's subsequent loads see published data.
        if (threadIdx.x < 8) {
            while (__hip_atomic_load(fl + q + threadIdx.x, __ATOMIC_ACQUIRE,
                                     __HIP_MEMORY_SCOPE_AGENT) == 0u) {
                __builtin_amdgcn_s_sleep(1);
            }
        }
        float4 l[8];
#pragma unroll
        for (int j = 0; j < 8; ++j) l[j] = *(const float4*)(cl + (size_t)(q + j) * C);
#pragma unroll
        for (int j = 0; j < 8; ++j) {
            s.x = fmaf(aLx, s.x, l[j].x);
            s.y = fmaf(aLy, s.y, l[j].y);
            s.z = fmaf(aLz, s.z, l[j].z);
            s.w = fmaf(aLw, s.w, l[j].w);
        }
    }
    for (; q < p; ++q) {
        while (__hip_atomic_load(fl + q, __ATOMIC_ACQUIRE,
                                 __HIP_MEMORY_SCOPE_AGENT) == 0u) {
            __builtin_amdgcn_s_sleep(1);
        }
        float4 l = *(const float4*)(cl + (size_t)q * C);
        s.x = fmaf(aLx, s.x, l.x);
        s.y = fmaf(aLy, s.y, l.y);
        s.z = fmaf(aLz, s.z, l.z);
        s.w = fmaf(aLw, s.w, l.w);
    }

    // ---- phase B: re-stream this chunk seeded with s (x L2/L3-warm) ----
    float4* op = (float4*)(out + base) + threadIdx.x;
    float yb0 = s.x, yb1 = s.y, yb2 = s.z, yb3 = s.w;
    for (int i0 = 0; i0 < CHUNK_L; i0 += 8) {
        float4 xv[8];
#pragma unroll
        for (int j = 0; j < 8; ++j) xv[j] = xp[(size_t)(i0 + j) * sF4];
#pragma unroll
        for (int j = 0; j < 8; ++j) {
            yb0 = fmaf(ax, yb0, w4.x * xv[j].x);
            yb1 = fmaf(ay, yb1, w4.y * xv[j].y);
            yb2 = fmaf(az, yb2, w4.z * xv[j].z);
            yb3 = fmaf(aw, yb3, w4.w * xv[j].w);
            float4 r; r.x = yb0; r.y = yb1; r.z = yb2; r.w = yb3;
            op[(size_t)(i0 + j) * sF4] = r;
        }
    }
}

extern "C" void kernel_launch(void* const* d_in, const int* in_sizes, int n_in,
                              void* d_out, int out_size, void* d_ws, size_t ws_size,
                              hipStream_t stream) {
    const float* x      = (const float*)d_in[0];  // [B, T, C]
    const float* init   = (const float*)d_in[1];  // [B, C]
    const float* smooth = (const float*)d_in[2];  // [C]
    float* out = (float*)d_out;

    const int C  = in_sizes[2];
    const int BC = in_sizes[1];
    const int B  = BC / C;
    const int T  = in_sizes[0] / BC;
    const int P  = T / CHUNK_L;

    float* chunk_last = (float*)d_ws;                               // [B, P, C]
    unsigned int* flags =
        (unsigned int*)((char*)d_ws + (size_t)B * P * C * sizeof(float));  // [B*P]

    // Workspace is poisoned by the harness each iteration: flags MUST be
    // zeroed before the kernel (8 KiB, async, graph-capturable).
    hipMemsetAsync(flags, 0, (size_t)B * P * sizeof(unsigned int), stream);

    ema_fused<<<dim3(B * P), dim3(C / 4), 0, stream>>>(
        x, smooth, init, out, chunk_last, flags, T, C, P);
}

// Round 3
// 319.603 us; speedup vs baseline: 1.6377x; 1.6377x over previous
//
#include <hip/hip_runtime.h>

// EMA y_t = w*x_t + (1-w)*y_{t-1}, a = 1-w per-channel constant.
// SINGLE fused kernel, chunk length L=64, P = T/L = 128 chunks per batch row.
// Decoupled lookback with HOISTED fences:
//   producer: normal stores -> ONE release fence (vmcnt+wbl2) -> relaxed flag
//   consumer: relaxed spin on flags (no cache maintenance) -> ONE acquire
//             fence (buffer_inv) -> normal cached reads of aggregates.
//
// Round-1 lesson (measured): acquire per spin-iteration = L2-invalidate storm
//   -> 0.9% VALUBusy, 366 us. Same primitives, hoisted to once per block.
// Round-2 lesson: relaxed-only data-as-flag sync (unverified sc1 coherence)
//   hung the container. Never spin on an unproven visibility mechanism.

#define CHUNK_L 64

__device__ __forceinline__ float clip01(float v) {
    return fminf(fmaxf(v, 0.0f), 1.0f);
}

__global__ __launch_bounds__(64) void ema_fused(
    const float* __restrict__ x, const float* __restrict__ smooth,
    const float* __restrict__ init, float* __restrict__ out,
    float* __restrict__ chunk_last, unsigned int* __restrict__ flags,
    int T, int C, int P) {
    const int blk = blockIdx.x;          // b*P + p
    const int b = blk / P;
    const int p = blk - b * P;
    const int t = threadIdx.x;
    const int c = t << 2;

    float4 w4 = *(const float4*)(smooth + c);
    w4.x = clip01(w4.x); w4.y = clip01(w4.y); w4.z = clip01(w4.z); w4.w = clip01(w4.w);
    const float ax = 1.0f - w4.x, ay = 1.0f - w4.y, az = 1.0f - w4.z, aw = 1.0f - w4.w;

    const int sF4 = C >> 2;
    const size_t base = ((size_t)b * T + (size_t)p * CHUNK_L) * C;
    const float4* xp = (const float4*)(x + base) + t;

    // ---- phase A: zero-seeded local scan -> chunk aggregate ----
    float y0 = 0.0f, y1 = 0.0f, y2 = 0.0f, y3 = 0.0f;
    for (int i0 = 0; i0 < CHUNK_L; i0 += 8) {
        float4 xv[8];
#pragma unroll
        for (int j = 0; j < 8; ++j) xv[j] = xp[(size_t)(i0 + j) * sF4];
#pragma unroll
        for (int j = 0; j < 8; ++j) {
            y0 = fmaf(ax, y0, w4.x * xv[j].x);
            y1 = fmaf(ay, y1, w4.y * xv[j].y);
            y2 = fmaf(az, y2, w4.z * xv[j].z);
            y3 = fmaf(aw, y3, w4.w * xv[j].w);
        }
    }
    {
        float4 r; r.x = y0; r.y = y1; r.z = y2; r.w = y3;
        *(float4*)(chunk_last + (size_t)blk * C + c) = r;
    }
    // ONE release fence per block: drains the aggregate stores and writes
    // dirty L2 lines back to the coherence point, then publish the flag
    // with a cheap relaxed (sc1) store.
    __builtin_amdgcn_fence(__ATOMIC_RELEASE, "agent");
    if (t == 0) {
        __hip_atomic_store(flags + blk, 1u, __ATOMIC_RELAXED, __HIP_MEMORY_SCOPE_AGENT);
    }

    // aL = a^CHUNK_L by repeated squaring (6 squarings for L=64)
    float aLx = ax, aLy = ay, aLz = az, aLw = aw;
    for (int e = CHUNK_L; e > 1; e >>= 1) { aLx *= aLx; aLy *= aLy; aLz *= aLz; aLw *= aLw; }

    // ---- carry-in: wait for ALL predecessors, then one acquire fence ----
    float4 s = *(const float4*)(init + (size_t)b * C + c);
    if (p > 0) {
        const unsigned int* fl = flags + (size_t)b * P;
        for (;;) {
            bool all_set = true;
            for (int q0 = 0; q0 < p; q0 += 64) {
                const int qq = q0 + t;
                const unsigned int f =
                    (qq < p) ? __hip_atomic_load(fl + qq, __ATOMIC_RELAXED,
                                                 __HIP_MEMORY_SCOPE_AGENT)
                             : 1u;
                all_set &= (f != 0u);
            }
            if (__all((int)all_set)) break;
            __builtin_amdgcn_s_sleep(4);
        }
        // ONE acquire fence per block: invalidate stale lines so the normal
        // cached loads below observe the released aggregates.
        __builtin_amdgcn_fence(__ATOMIC_ACQUIRE, "agent");

        const float* cl = chunk_last + (size_t)b * P * C + c;
        int q = 0;
        for (; q + 8 <= p; q += 8) {
            float4 l[8];
#pragma unroll
            for (int j = 0; j < 8; ++j) l[j] = *(const float4*)(cl + (size_t)(q + j) * C);
#pragma unroll
            for (int j = 0; j < 8; ++j) {
                s.x = fmaf(aLx, s.x, l[j].x);
                s.y = fmaf(aLy, s.y, l[j].y);
                s.z = fmaf(aLz, s.z, l[j].z);
                s.w = fmaf(aLw, s.w, l[j].w);
            }
        }
        for (; q < p; ++q) {
            float4 l = *(const float4*)(cl + (size_t)q * C);
            s.x = fmaf(aLx, s.x, l.x);
            s.y = fmaf(aLy, s.y, l.y);
            s.z = fmaf(aLz, s.z, l.z);
            s.w = fmaf(aLw, s.w, l.w);
        }
    }

    // ---- phase B: re-stream this chunk seeded with s (x L3-warm) ----
    float4* op = (float4*)(out + base) + t;
    float yb0 = s.x, yb1 = s.y, yb2 = s.z, yb3 = s.w;
    for (int i0 = 0; i0 < CHUNK_L; i0 += 8) {
        float4 xv[8];
#pragma unroll
        for (int j = 0; j < 8; ++j) xv[j] = xp[(size_t)(i0 + j) * sF4];
#pragma unroll
        for (int j = 0; j < 8; ++j) {
            yb0 = fmaf(ax, yb0, w4.x * xv[j].x);
            yb1 = fmaf(ay, yb1, w4.y * xv[j].y);
            yb2 = fmaf(az, yb2, w4.z * xv[j].z);
            yb3 = fmaf(aw, yb3, w4.w * xv[j].w);
            float4 r; r.x = yb0; r.y = yb1; r.z = yb2; r.w = yb3;
            op[(size_t)(i0 + j) * sF4] = r;
        }
    }
}

extern "C" void kernel_launch(void* const* d_in, const int* in_sizes, int n_in,
                              void* d_out, int out_size, void* d_ws, size_t ws_size,
                              hipStream_t stream) {
    const float* x      = (const float*)d_in[0];  // [B, T, C]
    const float* init   = (const float*)d_in[1];  // [B, C]
    const float* smooth = (const float*)d_in[2];  // [C]
    float* out = (float*)d_out;

    const int C  = in_sizes[2];
    const int BC = in_sizes[1];
    const int B  = BC / C;
    const int T  = in_sizes[0] / BC;
    const int P  = T / CHUNK_L;

    float* chunk_last = (float*)d_ws;                               // [B, P, C]
    unsigned int* flags =
        (unsigned int*)((char*)d_ws + (size_t)B * P * C * sizeof(float));  // [B*P]

    // Workspace is poisoned each iteration: flags MUST be zeroed before the
    // kernel (8 KiB, plain byte memset — proven graph-capturable in round 1).
    hipMemsetAsync(flags, 0, (size_t)B * P * sizeof(unsigned int), stream);

    ema_fused<<<dim3(B * P), dim3(C / 4), 0, stream>>>(
        x, smooth, init, out, chunk_last, flags, T, C, P);
}

// Round 4
// 273.862 us; speedup vs baseline: 1.9113x; 1.1670x over previous
//
#include <hip/hip_runtime.h>

// EMA y_t = w*x_t + (1-w)*y_{t-1}, a = 1-w per-channel constant.
// SINGLE fused kernel, chunk length L=64, P = T/L = 128 chunks per batch row.
// FENCE-FREE decoupled lookback (no buffer_wbl2 / buffer_inv at all):
//   producer: aggregate via 2x relaxed agent-scope u64 atomic stores
//             (sc1, write-through to the coherent MALL), s_waitcnt vmcnt(0),
//             then relaxed flag store (primitive proven in round 3).
//   consumer: relaxed flag spin (proven to observe remote sc1 stores
//             cross-XCD WITHOUT any acquire - round 3 passed), then relaxed
//             agent-scope u64 atomic loads of the aggregates, VALIDATED
//             against the 0xFF..F sentinel (two -NaNs, unreachable from
//             finite FMA math; each u64 store is all-or-nothing).
// Correctness does not rest on any unverified ordering: the sentinel check
// re-loads until data is valid.
//
// Round-1 lesson: acquire/release per spin iteration = cache storm (366 us).
// Round-3 lesson: even ONE wbl2+inv per block is an XCD-wide L2 flush x512
//   per XCD -> x streams evicted, 157 us @ 2% VALUBusy. Hence: zero fences.
// Round-2 lesson: hipMemsetD32Async is unproven under graph capture; only
//   byte-pattern hipMemsetAsync is used here.

#define CHUNK_L 64
#define SENTI64 0xFFFFFFFFFFFFFFFFull

__device__ __forceinline__ float clip01(float v) {
    return fminf(fmaxf(v, 0.0f), 1.0f);
}

__global__ __launch_bounds__(64) void ema_fused(
    const float* __restrict__ x, const float* __restrict__ smooth,
    const float* __restrict__ init, float* __restrict__ out,
    float* __restrict__ chunk_last, unsigned int* __restrict__ flags,
    int T, int C, int P) {
    const int blk = blockIdx.x;          // b*P + p
    const int b = blk / P;
    const int p = blk - b * P;
    const int t = threadIdx.x;
    const int c = t << 2;

    float4 w4 = *(const float4*)(smooth + c);
    w4.x = clip01(w4.x); w4.y = clip01(w4.y); w4.z = clip01(w4.z); w4.w = clip01(w4.w);
    const float ax = 1.0f - w4.x, ay = 1.0f - w4.y, az = 1.0f - w4.z, aw = 1.0f - w4.w;

    const int sF4 = C >> 2;
    const size_t base = ((size_t)b * T + (size_t)p * CHUNK_L) * C;
    const float4* xp = (const float4*)(x + base) + t;

    // ---- phase A: zero-seeded local scan -> chunk aggregate ----
    float y0 = 0.0f, y1 = 0.0f, y2 = 0.0f, y3 = 0.0f;
    for (int i0 = 0; i0 < CHUNK_L; i0 += 8) {
        float4 xv[8];
#pragma unroll
        for (int j = 0; j < 8; ++j) xv[j] = xp[(size_t)(i0 + j) * sF4];
#pragma unroll
        for (int j = 0; j < 8; ++j) {
            y0 = fmaf(ax, y0, w4.x * xv[j].x);
            y1 = fmaf(ay, y1, w4.y * xv[j].y);
            y2 = fmaf(az, y2, w4.z * xv[j].z);
            y3 = fmaf(aw, y3, w4.w * xv[j].w);
        }
    }
    // Publish aggregate: relaxed agent-scope (sc1) u64 stores go through to
    // the MALL coherence point. No fence; no L2 cache maintenance.
    {
        union { float f[4]; unsigned long long u[2]; } r;
        r.f[0] = y0; r.f[1] = y1; r.f[2] = y2; r.f[3] = y3;
        unsigned long long* dst =
            (unsigned long long*)(chunk_last + (size_t)blk * C + c);
        __hip_atomic_store(dst + 0, r.u[0], __ATOMIC_RELAXED, __HIP_MEMORY_SCOPE_AGENT);
        __hip_atomic_store(dst + 1, r.u[1], __ATOMIC_RELAXED, __HIP_MEMORY_SCOPE_AGENT);
    }
    // Wave-local drain so the flag (performance gate) trails the data in the
    // common case; correctness is covered by the sentinel validation below.
    asm volatile("s_waitcnt vmcnt(0)" ::: "memory");
    if (t == 0) {
        __hip_atomic_store(flags + blk, 1u, __ATOMIC_RELAXED, __HIP_MEMORY_SCOPE_AGENT);
    }

    // aL = a^CHUNK_L by repeated squaring (6 squarings for L=64)
    float aLx = ax, aLy = ay, aLz = az, aLw = aw;
    for (int e = CHUNK_L; e > 1; e >>= 1) { aLx *= aLx; aLy *= aLy; aLz *= aLz; aLw *= aLw; }

    // ---- carry-in: flag spin, then validated sc1 lookback ----
    float4 s = *(const float4*)(init + (size_t)b * C + c);
    if (p > 0) {
        const unsigned int* fl = flags + (size_t)b * P;
        for (;;) {
            bool all_set = true;
            for (int q0 = 0; q0 < p; q0 += 64) {
                const int qq = q0 + t;
                const unsigned int f =
                    (qq < p) ? __hip_atomic_load(fl + qq, __ATOMIC_RELAXED,
                                                 __HIP_MEMORY_SCOPE_AGENT)
                             : 1u;
                all_set &= (f != 0u);
            }
            if (__all((int)all_set)) break;
            __builtin_amdgcn_s_sleep(4);
        }
        asm volatile("" ::: "memory");   // compiler barrier only; no cache op

        const unsigned long long* cl =
            (const unsigned long long*)(chunk_last + (size_t)b * P * C + c);
        const int sU64 = C >> 1;         // u64 stride per chunk row
        int q = 0;
        for (; q + 8 <= p; q += 8) {
            union { float f[4]; unsigned long long u[2]; } l[8];
            for (;;) {
                bool ok = true;
#pragma unroll
                for (int j = 0; j < 8; ++j) {
                    const unsigned long long* src = cl + (size_t)(q + j) * sU64;
                    l[j].u[0] = __hip_atomic_load(src + 0, __ATOMIC_RELAXED,
                                                  __HIP_MEMORY_SCOPE_AGENT);
                    l[j].u[1] = __hip_atomic_load(src + 1, __ATOMIC_RELAXED,
                                                  __HIP_MEMORY_SCOPE_AGENT);
                    ok &= (l[j].u[0] != SENTI64) & (l[j].u[1] != SENTI64);
                }
                if (__all((int)ok)) break;       // near-always first try
                __builtin_amdgcn_s_sleep(1);
            }
#pragma unroll
            for (int j = 0; j < 8; ++j) {
                s.x = fmaf(aLx, s.x, l[j].f[0]);
                s.y = fmaf(aLy, s.y, l[j].f[1]);
                s.z = fmaf(aLz, s.z, l[j].f[2]);
                s.w = fmaf(aLw, s.w, l[j].f[3]);
            }
        }
        for (; q < p; ++q) {
            union { float f[4]; unsigned long long u[2]; } l;
            const unsigned long long* src = cl + (size_t)q * sU64;
            for (;;) {
                l.u[0] = __hip_atomic_load(src + 0, __ATOMIC_RELAXED,
                                           __HIP_MEMORY_SCOPE_AGENT);
                l.u[1] = __hip_atomic_load(src + 1, __ATOMIC_RELAXED,
                                           __HIP_MEMORY_SCOPE_AGENT);
                if (__all((int)((l.u[0] != SENTI64) & (l.u[1] != SENTI64)))) break;
                __builtin_amdgcn_s_sleep(1);
            }
            s.x = fmaf(aLx, s.x, l.f[0]);
            s.y = fmaf(aLy, s.y, l.f[1]);
            s.z = fmaf(aLz, s.z, l.f[2]);
            s.w = fmaf(aLw, s.w, l.f[3]);
        }
    }

    // ---- phase B: re-stream this chunk seeded with s (x L2/L3-warm) ----
    float4* op = (float4*)(out + base) + t;
    float yb0 = s.x, yb1 = s.y, yb2 = s.z, yb3 = s.w;
    for (int i0 = 0; i0 < CHUNK_L; i0 += 8) {
        float4 xv[8];
#pragma unroll
        for (int j = 0; j < 8; ++j) xv[j] = xp[(size_t)(i0 + j) * sF4];
#pragma unroll
        for (int j = 0; j < 8; ++j) {
            yb0 = fmaf(ax, yb0, w4.x * xv[j].x);
            yb1 = fmaf(ay, yb1, w4.y * xv[j].y);
            yb2 = fmaf(az, yb2, w4.z * xv[j].z);
            yb3 = fmaf(aw, yb3, w4.w * xv[j].w);
            float4 r; r.x = yb0; r.y = yb1; r.z = yb2; r.w = yb3;
            op[(size_t)(i0 + j) * sF4] = r;
        }
    }
}

extern "C" void kernel_launch(void* const* d_in, const int* in_sizes, int n_in,
                              void* d_out, int out_size, void* d_ws, size_t ws_size,
                              hipStream_t stream) {
    const float* x      = (const float*)d_in[0];  // [B, T, C]
    const float* init   = (const float*)d_in[1];  // [B, C]
    const float* smooth = (const float*)d_in[2];  // [C]
    float* out = (float*)d_out;

    const int C  = in_sizes[2];
    const int BC = in_sizes[1];
    const int B  = BC / C;
    const int T  = in_sizes[0] / BC;
    const int P  = T / CHUNK_L;

    float* chunk_last = (float*)d_ws;                               // [B, P, C]
    unsigned int* flags =
        (unsigned int*)((char*)d_ws + (size_t)B * P * C * sizeof(float));  // [B*P]

    // Workspace is poisoned each iteration. Byte-pattern hipMemsetAsync only
    // (round-2 lesson): chunk_last -> 0xFF sentinel (2 MB), flags -> 0 (8 KB).
    hipMemsetAsync(chunk_last, 0xFF, (size_t)B * P * C * sizeof(float), stream);
    hipMemsetAsync(flags, 0, (size_t)B * P * sizeof(unsigned int), stream);

    ema_fused<<<dim3(B * P), dim3(C / 4), 0, stream>>>(
        x, smooth, init, out, chunk_last, flags, T, C, P);
}